// Round 1
// baseline (786.069 us; speedup 1.0000x reference)
//
#include <hip/hip_runtime.h>
#include <math.h>

#define B_    4
#define CIN   256
#define COUT  256
#define KK_   9
#define SD    512
#define H_    64
#define W_    64
#define HW    4096
#define KTOT  2304   // CIN*KK
#define SCALE_     0.0208333333333333332f   // 1/sqrt(256*9)
#define MOD_SCALE_ 0.04419417382415922f     // 1/sqrt(512)
#define SQRT2_     1.4142135623730951f

// ---------------- kernel 1: style modulation ----------------
__global__ void k_style(const float* __restrict__ style, const float* __restrict__ mod_w,
                        const float* __restrict__ mod_b, float* __restrict__ s_buf) {
    int b = blockIdx.x, c = threadIdx.x;
    const float* st = style + b * SD;
    const float* mw = mod_w + c * SD;
    float acc = 0.f;
    for (int d = 0; d < SD; ++d) acc += st[d] * mw[d];
    s_buf[b * CIN + c] = acc * MOD_SCALE_ + mod_b[c];
}

// ---------------- kernel 2: demodulated weights, K-major transposed ----------------
// wgtT[b][k][o], k = c*9 + kk
__global__ void k_wgt(const float* __restrict__ weight, const float* __restrict__ s_buf,
                      float* __restrict__ wgtT) {
    int o = blockIdx.x, b = blockIdx.y;
    int c = threadIdx.x;
    float s = s_buf[b * CIN + c];
    const float* wp = weight + (o * CIN + c) * KK_;
    float w[KK_];
    float p = 0.f;
#pragma unroll
    for (int i = 0; i < KK_; ++i) { w[i] = SCALE_ * wp[i] * s; p += w[i] * w[i]; }
    __shared__ float red[256];
    red[c] = p;
    __syncthreads();
    for (int s2 = 128; s2 > 0; s2 >>= 1) {
        if (c < s2) red[c] += red[c + s2];
        __syncthreads();
    }
    float demod = rsqrtf(red[0] + 1e-8f);
#pragma unroll
    for (int i = 0; i < KK_; ++i) {
        wgtT[((size_t)b * KTOT + c * KK_ + i) * COUT + o] = w[i] * demod;
    }
}

// ---------------- kernel 3: deformable sampling + GEMM + fused bias/lrelu ----------------
// grid: (64 rows, 4 o-tiles, 4 batches), block 256.
// C-tile: 64 outputs x 64 pixels (one image row). Thread (ty,tx) -> 4x4 micro-tile.
__global__ __launch_bounds__(256) void k_gemm(
    const float* __restrict__ in, const float* __restrict__ off,
    const float* __restrict__ msk, const float* __restrict__ wgtT,
    const float* __restrict__ bias1, const float* __restrict__ bias2,
    float* __restrict__ mid) {
    const int b   = blockIdx.z;
    const int bo0 = blockIdx.y * 64;
    const int y   = blockIdx.x;           // one image row per block
    const int tid = threadIdx.x;

    __shared__ float tw [4][KK_][64];     // bilinear corner weights (mask folded)
    __shared__ int   tix[4][KK_][64];     // clamped gather indices
    __shared__ float wt[32][64];          // wgt tile  [k][o]
    __shared__ float st[32][64];          // smp tile  [k][p]

    // ---- taps: 9 kk x 64 pixels ----
    for (int e = tid; e < KK_ * 64; e += 256) {
        int kk = e >> 6, x = e & 63;
        float oy = off[(((size_t)b * 2 * KK_ + 2 * kk + 0) * H_ + y) * W_ + x];
        float ox = off[(((size_t)b * 2 * KK_ + 2 * kk + 1) * H_ + y) * W_ + x];
        float m  = msk[(((size_t)b * KK_ + kk) * H_ + y) * W_ + x];
        float py = (float)(y + kk / 3 - 1) + oy;
        float px = (float)(x + kk % 3 - 1) + ox;
        float y0f = floorf(py), x0f = floorf(px);
        float dy = py - y0f, dx = px - x0f;
        int y0 = (int)y0f, x0 = (int)x0f;
        int y1 = y0 + 1, x1 = x0 + 1;
        bool vy0 = (y0 >= 0) & (y0 < H_), vy1 = (y1 >= 0) & (y1 < H_);
        bool vx0 = (x0 >= 0) & (x0 < W_), vx1 = (x1 >= 0) & (x1 < W_);
        int cy0 = min(max(y0, 0), H_ - 1), cy1 = min(max(y1, 0), H_ - 1);
        int cx0 = min(max(x0, 0), W_ - 1), cx1 = min(max(x1, 0), W_ - 1);
        float wy0 = 1.f - dy, wy1 = dy, wx0 = 1.f - dx, wx1 = dx;
        tw[0][kk][x] = (vy0 && vx0) ? m * wy0 * wx0 : 0.f;  tix[0][kk][x] = cy0 * W_ + cx0;
        tw[1][kk][x] = (vy0 && vx1) ? m * wy0 * wx1 : 0.f;  tix[1][kk][x] = cy0 * W_ + cx1;
        tw[2][kk][x] = (vy1 && vx0) ? m * wy1 * wx0 : 0.f;  tix[2][kk][x] = cy1 * W_ + cx0;
        tw[3][kk][x] = (vy1 && vx1) ? m * wy1 * wx1 : 0.f;  tix[3][kk][x] = cy1 * W_ + cx1;
    }

    float acc[4][4] = {};
    const float* inb = in + (size_t)b * CIN * HW;
    const int ty = tid >> 4, tx = tid & 15;

    for (int k0 = 0; k0 < KTOT; k0 += 32) {
        __syncthreads();   // taps ready (iter 0) / previous tiles consumed
        const float* wsrc = wgtT + ((size_t)b * KTOT + k0) * COUT + bo0;
        for (int v = tid; v < 2048; v += 256) {
            int k = v >> 6, o = v & 63;
            wt[k][o] = wsrc[(size_t)k * COUT + o];
        }
        for (int v = tid; v < 2048; v += 256) {
            int k = v >> 6, p = v & 63;
            int kg = k0 + k;
            int c = kg / 9, kk = kg - c * 9;
            const float* inc = inb + c * HW;
            st[k][p] = tw[0][kk][p] * inc[tix[0][kk][p]]
                     + tw[1][kk][p] * inc[tix[1][kk][p]]
                     + tw[2][kk][p] * inc[tix[2][kk][p]]
                     + tw[3][kk][p] * inc[tix[3][kk][p]];
        }
        __syncthreads();
#pragma unroll
        for (int k = 0; k < 32; ++k) {
            float4 w4 = *(const float4*)&wt[k][ty * 4];
            float4 s4 = *(const float4*)&st[k][tx * 4];
            acc[0][0] += w4.x * s4.x; acc[0][1] += w4.x * s4.y; acc[0][2] += w4.x * s4.z; acc[0][3] += w4.x * s4.w;
            acc[1][0] += w4.y * s4.x; acc[1][1] += w4.y * s4.y; acc[1][2] += w4.y * s4.z; acc[1][3] += w4.y * s4.w;
            acc[2][0] += w4.z * s4.x; acc[2][1] += w4.z * s4.y; acc[2][2] += w4.z * s4.z; acc[2][3] += w4.z * s4.w;
            acc[3][0] += w4.w * s4.x; acc[3][1] += w4.w * s4.y; acc[3][2] += w4.w * s4.z; acc[3][3] += w4.w * s4.w;
        }
    }

    // ---- epilogue: bias1 -> lrelu -> *sqrt2 -> bias2 -> lrelu -> *sqrt2 ----
#pragma unroll
    for (int i = 0; i < 4; ++i) {
        int o = bo0 + ty * 4 + i;
        float b1 = bias1[o], b2 = bias2[o];
        float4 r;
        float vv[4];
#pragma unroll
        for (int j = 0; j < 4; ++j) {
            float v = acc[i][j] + b1;
            v = (v > 0.f ? v : 0.2f * v) * SQRT2_;
            v = v + b2;
            v = (v > 0.f ? v : 0.2f * v) * SQRT2_;
            vv[j] = v;
        }
        r.x = vv[0]; r.y = vv[1]; r.z = vv[2]; r.w = vv[3];
        *(float4*)&mid[((size_t)(b * COUT + o)) * HW + y * W_ + tx * 4] = r;
    }
}

// ---------------- kernel 4: x2 upsample + FIR [1,3,3,1] blur ----------------
// Each output pixel = 2x2 weighted sum of mid, parity-dependent weights (1,3)/(3,1) per dim, /16.
__global__ void k_blur(const float* __restrict__ mid, float* __restrict__ out) {
    int idx = blockIdx.x * 256 + threadIdx.x;     // b*o*Y*X, 4*256*128*128
    int X = idx & 127;
    int Y = (idx >> 7) & 127;
    int bo = idx >> 14;
    const float* m = mid + (size_t)bo * HW;
    int ry0, ry1; float wy0, wy1;
    if (Y & 1) { ry0 = Y >> 1; wy0 = 3.f; ry1 = (Y >> 1) + 1; wy1 = 1.f; }
    else       { ry0 = (Y >> 1) - 1; wy0 = 1.f; ry1 = Y >> 1; wy1 = 3.f; }
    int rx0, rx1; float wx0, wx1;
    if (X & 1) { rx0 = X >> 1; wx0 = 3.f; rx1 = (X >> 1) + 1; wx1 = 1.f; }
    else       { rx0 = (X >> 1) - 1; wx0 = 1.f; rx1 = X >> 1; wx1 = 3.f; }
    bool vy0 = (ry0 >= 0) & (ry0 < H_), vy1 = (ry1 >= 0) & (ry1 < H_);
    bool vx0 = (rx0 >= 0) & (rx0 < W_), vx1 = (rx1 >= 0) & (rx1 < W_);
    float acc = 0.f;
    if (vy0) {
        const float* r = m + ry0 * W_;
        if (vx0) acc += wy0 * wx0 * r[rx0];
        if (vx1) acc += wy0 * wx1 * r[rx1];
    }
    if (vy1) {
        const float* r = m + ry1 * W_;
        if (vx0) acc += wy1 * wx0 * r[rx0];
        if (vx1) acc += wy1 * wx1 * r[rx1];
    }
    out[idx] = acc * (1.f / 16.f);
}

// ---------------- launch ----------------
extern "C" void kernel_launch(void* const* d_in, const int* in_sizes, int n_in,
                              void* d_out, int out_size, void* d_ws, size_t ws_size,
                              hipStream_t stream) {
    const float* input  = (const float*)d_in[0];
    const float* style  = (const float*)d_in[1];
    const float* offset = (const float*)d_in[2];
    const float* mask   = (const float*)d_in[3];
    const float* weight = (const float*)d_in[4];
    const float* mod_w  = (const float*)d_in[5];
    const float* mod_b  = (const float*)d_in[6];
    const float* bias1  = (const float*)d_in[7];
    const float* bias2  = (const float*)d_in[8];
    float* out = (float*)d_out;

    // workspace layout (floats): s_buf[1024] | wgtT[4*2304*256] | mid[4*256*4096]  = 26.2 MB
    float* ws    = (float*)d_ws;
    float* s_buf = ws;
    float* wgtT  = ws + 1024;
    float* mid   = wgtT + (size_t)B_ * KTOT * COUT;

    k_style<<<dim3(B_), dim3(256), 0, stream>>>(style, mod_w, mod_b, s_buf);
    k_wgt  <<<dim3(COUT, B_), dim3(256), 0, stream>>>(weight, s_buf, wgtT);
    k_gemm <<<dim3(H_, COUT / 64, B_), dim3(256), 0, stream>>>(input, offset, mask, wgtT,
                                                               bias1, bias2, mid);
    k_blur <<<dim3((B_ * COUT * 128 * 128) / 256), dim3(256), 0, stream>>>(mid, out);
}

// Round 2
// 239.272 us; speedup vs baseline: 3.2852x; 3.2852x over previous
//
#include <hip/hip_runtime.h>
#include <math.h>

typedef __bf16 bf16x8 __attribute__((ext_vector_type(8)));
typedef float  f32x4  __attribute__((ext_vector_type(4)));

#define B_    4
#define CIN   256
#define COUT  256
#define KK_   9
#define SD    512
#define H_    64
#define W_    64
#define HW    4096
#define KTOT  2304   // CIN*KK
#define SCALE_     0.0208333333333333332f   // 1/sqrt(256*9)
#define MOD_SCALE_ 0.04419417382415922f     // 1/sqrt(512)
#define SQRT2_     1.4142135623730951f

__device__ __forceinline__ unsigned short f2bf(float f) {
    union { float f; unsigned int u; } v; v.f = f;
    unsigned int r = v.u + 0x7FFFu + ((v.u >> 16) & 1u);   // RNE
    return (unsigned short)(r >> 16);
}

__device__ __forceinline__ void gload_lds16(const void* g, void* l) {
    __builtin_amdgcn_global_load_lds(
        (const __attribute__((address_space(1))) unsigned int*)g,
        (__attribute__((address_space(3))) unsigned int*)l, 16, 0, 0);
}

// ---------------- kernel 1: style modulation ----------------
__global__ void k_style(const float* __restrict__ style, const float* __restrict__ mod_w,
                        const float* __restrict__ mod_b, float* __restrict__ s_buf) {
    int b = blockIdx.x, c = threadIdx.x;
    const float* st = style + b * SD;
    const float* mw = mod_w + c * SD;
    float acc = 0.f;
    for (int d = 0; d < SD; ++d) acc += st[d] * mw[d];
    s_buf[b * CIN + c] = acc * MOD_SCALE_ + mod_b[c];
}

// ---------------- kernel 2: demodulated weights, bf16, o-major ----------------
// wgtT2[b][o][k], k = c*9 + kk  (k contiguous)
__global__ void k_wgt(const float* __restrict__ weight, const float* __restrict__ s_buf,
                      unsigned short* __restrict__ wgtT2) {
    int o = blockIdx.x, b = blockIdx.y;
    int c = threadIdx.x;
    float s = s_buf[b * CIN + c];
    const float* wp = weight + (o * CIN + c) * KK_;
    float w[KK_];
    float p = 0.f;
#pragma unroll
    for (int i = 0; i < KK_; ++i) { w[i] = SCALE_ * wp[i] * s; p += w[i] * w[i]; }
    __shared__ float red[256];
    red[c] = p;
    __syncthreads();
    for (int s2 = 128; s2 > 0; s2 >>= 1) {
        if (c < s2) red[c] += red[c + s2];
        __syncthreads();
    }
    float demod = rsqrtf(red[0] + 1e-8f);
    unsigned short* dst = wgtT2 + ((size_t)(b * COUT + o)) * KTOT + c * KK_;
#pragma unroll
    for (int i = 0; i < KK_; ++i) dst[i] = f2bf(w[i] * demod);
}

// ---------------- kernel 3: deformable im2col -> smpT[b][p][k] bf16 ----------------
// grid (64 rows, 8 c-chunks, 4 batches), block 256.
__global__ __launch_bounds__(256) void k_im2col(
    const float* __restrict__ in, const float* __restrict__ off,
    const float* __restrict__ msk, unsigned short* __restrict__ smpT) {
    const int y     = blockIdx.x;
    const int chunk = blockIdx.y;      // 32 channels per chunk
    const int b     = blockIdx.z;
    const int tid   = threadIdx.x;

    __shared__ float tw [4][KK_][64];
    __shared__ int   tix[4][KK_][64];
    __shared__ float buf[72][65];      // 8 channels x 9 taps = 72 k, padded

    // taps for this row (9 kk x 64 px)
    for (int e = tid; e < KK_ * 64; e += 256) {
        int kk = e >> 6, x = e & 63;
        float oy = off[(((size_t)b * 2 * KK_ + 2 * kk + 0) * H_ + y) * W_ + x];
        float ox = off[(((size_t)b * 2 * KK_ + 2 * kk + 1) * H_ + y) * W_ + x];
        float m  = msk[(((size_t)b * KK_ + kk) * H_ + y) * W_ + x];
        float py = (float)(y + kk / 3 - 1) + oy;
        float px = (float)(x + kk % 3 - 1) + ox;
        float y0f = floorf(py), x0f = floorf(px);
        float dy = py - y0f, dx = px - x0f;
        int y0 = (int)y0f, x0 = (int)x0f;
        int y1 = y0 + 1, x1 = x0 + 1;
        bool vy0 = (y0 >= 0) & (y0 < H_), vy1 = (y1 >= 0) & (y1 < H_);
        bool vx0 = (x0 >= 0) & (x0 < W_), vx1 = (x1 >= 0) & (x1 < W_);
        int cy0 = min(max(y0, 0), H_ - 1), cy1 = min(max(y1, 0), H_ - 1);
        int cx0 = min(max(x0, 0), W_ - 1), cx1 = min(max(x1, 0), W_ - 1);
        float wy0 = 1.f - dy, wy1 = dy, wx0 = 1.f - dx, wx1 = dx;
        tw[0][kk][x] = (vy0 && vx0) ? m * wy0 * wx0 : 0.f;  tix[0][kk][x] = cy0 * W_ + cx0;
        tw[1][kk][x] = (vy0 && vx1) ? m * wy0 * wx1 : 0.f;  tix[1][kk][x] = cy0 * W_ + cx1;
        tw[2][kk][x] = (vy1 && vx0) ? m * wy1 * wx0 : 0.f;  tix[2][kk][x] = cy1 * W_ + cx0;
        tw[3][kk][x] = (vy1 && vx1) ? m * wy1 * wx1 : 0.f;  tix[3][kk][x] = cy1 * W_ + cx1;
    }
    __syncthreads();

    const float* inb = in + (size_t)b * CIN * HW;
    const int c0 = chunk * 32;

    for (int sc = 0; sc < 4; ++sc) {
        const int cbase = c0 + sc * 8;
        // compute 72 k x 64 p, lanes = consecutive pixels (coalesced gathers)
#pragma unroll
        for (int i = 0; i < 18; ++i) {
            int e = tid + 256 * i;
            int kl = e >> 6, p = e & 63;
            int cc = kl / 9, kk = kl - cc * 9;
            const float* inc = inb + (cbase + cc) * HW;
            buf[kl][p] = tw[0][kk][p] * inc[tix[0][kk][p]]
                       + tw[1][kk][p] * inc[tix[1][kk][p]]
                       + tw[2][kk][p] * inc[tix[2][kk][p]]
                       + tw[3][kk][p] * inc[tix[3][kk][p]];
        }
        __syncthreads();
        // transposed write-out: lanes = consecutive k (coalesced stores)
        unsigned short* dst = smpT + ((size_t)(b * HW + y * 64)) * KTOT + cbase * KK_;
#pragma unroll
        for (int i = 0; i < 18; ++i) {
            int e = tid + 256 * i;
            int p = e / 72, kl = e - p * 72;
            dst[(size_t)p * KTOT + kl] = f2bf(buf[kl][p]);
        }
        __syncthreads();
    }
}

// ---------------- kernel 4: bf16 MFMA GEMM + fused bias/lrelu ----------------
// C[o][p] = sum_k W[o][k] * S[p][k].  Tile 128(O) x 64(P), BK=32, 4 waves.
__global__ __launch_bounds__(256) void k_gemm(
    const unsigned short* __restrict__ wgtT2, const unsigned short* __restrict__ smpT,
    const float* __restrict__ bias1, const float* __restrict__ bias2,
    float* __restrict__ mid) {
    const int p0 = blockIdx.x * 64;
    const int o0 = blockIdx.y * 128;
    const int b  = blockIdx.z;
    const int tid = threadIdx.x;
    const int w  = tid >> 6, l = tid & 63;
    const int lo = l & 15, lg = l >> 4;
    const int wr = w >> 1, wc = w & 1;     // wave -> (o half 64, p half 32)

    __shared__ unsigned short a_lds[128 * 32];   // [o][k] 64B rows
    __shared__ unsigned short b_lds[64 * 32];    // [p][k]

    const unsigned short* Abase = wgtT2 + ((size_t)(b * COUT + o0)) * KTOT;
    const unsigned short* Bbase = smpT  + ((size_t)(b * HW   + p0)) * KTOT;

    f32x4 acc[4][2] = {};

    for (int k0 = 0; k0 < KTOT; k0 += 32) {
        __syncthreads();
        // stage A (8KB = 8 x 1KB issues, 2 per wave) and B (4KB, 1 per wave)
        {
            const int j0 = 2 * w;
            const unsigned short* gA0 = Abase + (size_t)(j0 * 16 + (l >> 2)) * KTOT + k0 + (l & 3) * 8;
            gload_lds16(gA0, &a_lds[j0 * 512]);
            const unsigned short* gA1 = Abase + (size_t)((j0 + 1) * 16 + (l >> 2)) * KTOT + k0 + (l & 3) * 8;
            gload_lds16(gA1, &a_lds[(j0 + 1) * 512]);
            const unsigned short* gB = Bbase + (size_t)(w * 16 + (l >> 2)) * KTOT + k0 + (l & 3) * 8;
            gload_lds16(gB, &b_lds[w * 512]);
        }
        __syncthreads();

        bf16x8 af[4], bfr[2];
#pragma unroll
        for (int mi = 0; mi < 4; ++mi)
            af[mi] = *(const bf16x8*)&a_lds[(wr * 64 + mi * 16 + lo) * 32 + lg * 8];
#pragma unroll
        for (int ni = 0; ni < 2; ++ni)
            bfr[ni] = *(const bf16x8*)&b_lds[(wc * 32 + ni * 16 + lo) * 32 + lg * 8];
#pragma unroll
        for (int mi = 0; mi < 4; ++mi)
#pragma unroll
            for (int ni = 0; ni < 2; ++ni)
                acc[mi][ni] = __builtin_amdgcn_mfma_f32_16x16x32_bf16(af[mi], bfr[ni], acc[mi][ni], 0, 0, 0);
    }

    // epilogue: D element (reg r, lane l): o = lg*4+r, p = lo within each 16x16 frag
    float* mb = mid + ((size_t)b * COUT) * HW;
#pragma unroll
    for (int mi = 0; mi < 4; ++mi) {
        int obase = o0 + wr * 64 + mi * 16 + lg * 4;
#pragma unroll
        for (int ni = 0; ni < 2; ++ni) {
            int p = p0 + wc * 32 + ni * 16 + lo;
#pragma unroll
            for (int r = 0; r < 4; ++r) {
                int oo = obase + r;
                float v = acc[mi][ni][r] + bias1[oo];
                v = (v > 0.f ? v : 0.2f * v) * SQRT2_;
                v += bias2[oo];
                v = (v > 0.f ? v : 0.2f * v) * SQRT2_;
                mb[(size_t)oo * HW + p] = v;
            }
        }
    }
}

// ---------------- kernel 5: x2 upsample + FIR [1,3,3,1] blur ----------------
__global__ void k_blur(const float* __restrict__ mid, float* __restrict__ out) {
    int idx = blockIdx.x * 256 + threadIdx.x;     // 4*256*128*128
    int X = idx & 127;
    int Y = (idx >> 7) & 127;
    int bo = idx >> 14;
    const float* m = mid + (size_t)bo * HW;
    int ry0, ry1; float wy0, wy1;
    if (Y & 1) { ry0 = Y >> 1; wy0 = 3.f; ry1 = (Y >> 1) + 1; wy1 = 1.f; }
    else       { ry0 = (Y >> 1) - 1; wy0 = 1.f; ry1 = Y >> 1; wy1 = 3.f; }
    int rx0, rx1; float wx0, wx1;
    if (X & 1) { rx0 = X >> 1; wx0 = 3.f; rx1 = (X >> 1) + 1; wx1 = 1.f; }
    else       { rx0 = (X >> 1) - 1; wx0 = 1.f; rx1 = X >> 1; wx1 = 3.f; }
    bool vy0 = (ry0 >= 0) & (ry0 < H_), vy1 = (ry1 >= 0) & (ry1 < H_);
    bool vx0 = (rx0 >= 0) & (rx0 < W_), vx1 = (rx1 >= 0) & (rx1 < W_);
    float acc = 0.f;
    if (vy0) {
        const float* r = m + ry0 * W_;
        if (vx0) acc += wy0 * wx0 * r[rx0];
        if (vx1) acc += wy0 * wx1 * r[rx1];
    }
    if (vy1) {
        const float* r = m + ry1 * W_;
        if (vx0) acc += wy1 * wx0 * r[rx0];
        if (vx1) acc += wy1 * wx1 * r[rx1];
    }
    out[idx] = acc * (1.f / 16.f);
}

// ---------------- launch ----------------
extern "C" void kernel_launch(void* const* d_in, const int* in_sizes, int n_in,
                              void* d_out, int out_size, void* d_ws, size_t ws_size,
                              hipStream_t stream) {
    const float* input  = (const float*)d_in[0];
    const float* style  = (const float*)d_in[1];
    const float* offset = (const float*)d_in[2];
    const float* mask   = (const float*)d_in[3];
    const float* weight = (const float*)d_in[4];
    const float* mod_w  = (const float*)d_in[5];
    const float* mod_b  = (const float*)d_in[6];
    const float* bias1  = (const float*)d_in[7];
    const float* bias2  = (const float*)d_in[8];
    float* out = (float*)d_out;

    // ws layout (bytes): s_buf 4K | wgtT2 bf16 4.72M | smpT bf16 75.5M | mid f32 16.8M
    char* ws = (char*)d_ws;
    float*          s_buf = (float*)ws;
    unsigned short* wgtT2 = (unsigned short*)(ws + 4096);
    unsigned short* smpT  = (unsigned short*)(ws + 4096 + (size_t)B_ * COUT * KTOT * 2);
    float*          mid   = (float*)(ws + 4096 + (size_t)B_ * COUT * KTOT * 2
                                               + (size_t)B_ * HW * KTOT * 2);

    k_style <<<dim3(B_), dim3(256), 0, stream>>>(style, mod_w, mod_b, s_buf);
    k_wgt   <<<dim3(COUT, B_), dim3(256), 0, stream>>>(weight, s_buf, wgtT2);
    k_im2col<<<dim3(H_, CIN / 32, B_), dim3(256), 0, stream>>>(input, offset, mask, smpT);
    k_gemm  <<<dim3(HW / 64, COUT / 128, B_), dim3(256), 0, stream>>>(wgtT2, smpT, bias1, bias2, mid);
    k_blur  <<<dim3((B_ * COUT * 128 * 128) / 256), dim3(256), 0, stream>>>(mid, out);
}

// Round 3
// 140.578 us; speedup vs baseline: 5.5917x; 1.7021x over previous
//
#include <hip/hip_runtime.h>
#include <math.h>

typedef __bf16 bf16x8 __attribute__((ext_vector_type(8)));
typedef float  f32x4  __attribute__((ext_vector_type(4)));

#define B_    4
#define CIN   256
#define COUT  256
#define KK_   9
#define SD    512
#define H_    64
#define W_    64
#define HW    4096
#define KTOT  2304   // KK_*CIN ; k = kk*CIN + c
#define SCALE_     0.0208333333333333332f   // 1/sqrt(256*9)
#define MOD_SCALE_ 0.04419417382415922f     // 1/sqrt(512)
#define SQRT2_     1.4142135623730951f

__device__ __forceinline__ unsigned short f2bf(float f) {
    union { float f; unsigned int u; } v; v.f = f;
    unsigned int r = v.u + 0x7FFFu + ((v.u >> 16) & 1u);   // RNE
    return (unsigned short)(r >> 16);
}

__device__ __forceinline__ void gload_lds16(const void* g, void* l) {
    __builtin_amdgcn_global_load_lds(
        (const __attribute__((address_space(1))) unsigned int*)g,
        (__attribute__((address_space(3))) unsigned int*)l, 16, 0, 0);
}

// ---------------- kernel 1: style modulation ----------------
__global__ void k_style(const float* __restrict__ style, const float* __restrict__ mod_w,
                        const float* __restrict__ mod_b, float* __restrict__ s_buf) {
    int b = blockIdx.x, c = threadIdx.x;
    const float* st = style + b * SD;
    const float* mw = mod_w + c * SD;
    float acc = 0.f;
    for (int d = 0; d < SD; ++d) acc += st[d] * mw[d];
    s_buf[b * CIN + c] = acc * MOD_SCALE_ + mod_b[c];
}

// ---------------- kernel 2: demodulated weights, bf16, o-major ----------------
// wgtT2[b][o][k], k = kk*CIN + c
__global__ void k_wgt(const float* __restrict__ weight, const float* __restrict__ s_buf,
                      unsigned short* __restrict__ wgtT2) {
    int o = blockIdx.x, b = blockIdx.y;
    int c = threadIdx.x;
    float s = s_buf[b * CIN + c];
    const float* wp = weight + (o * CIN + c) * KK_;
    float w[KK_];
    float p = 0.f;
#pragma unroll
    for (int i = 0; i < KK_; ++i) { w[i] = SCALE_ * wp[i] * s; p += w[i] * w[i]; }
    __shared__ float red[256];
    red[c] = p;
    __syncthreads();
    for (int s2 = 128; s2 > 0; s2 >>= 1) {
        if (c < s2) red[c] += red[c + s2];
        __syncthreads();
    }
    float demod = rsqrtf(red[0] + 1e-8f);
    unsigned short* dst = wgtT2 + ((size_t)(b * COUT + o)) * KTOT + c;
#pragma unroll
    for (int i = 0; i < KK_; ++i) dst[(size_t)i * CIN] = f2bf(w[i] * demod);
}

// ---------------- kernel 2b: input transpose -> in_t[b][y][x][c] bf16 ----------------
// grid (64 y, 4 cchunk, 4 b), block 256. Tile: 64 c x 64 x for one row y.
__global__ __launch_bounds__(256) void k_tr(const float* __restrict__ in,
                                            unsigned short* __restrict__ in_t) {
    const int y = blockIdx.x, cc = blockIdx.y, b = blockIdx.z;
    const int tid = threadIdx.x;
    __shared__ unsigned short t[64][65];
    for (int e = tid; e < 4096; e += 256) {
        int c = e >> 6, x = e & 63;
        t[c][x] = f2bf(in[((size_t)(b * CIN + cc * 64 + c)) * HW + y * W_ + x]);
    }
    __syncthreads();
    for (int e = tid; e < 2048; e += 256) {
        int x = e >> 5, cp = e & 31;
        int c = cp * 2;
        unsigned int lo = t[c][x], hi = t[c + 1][x];
        unsigned int v = lo | (hi << 16);
        unsigned int* dst = (unsigned int*)(in_t + ((size_t)(b * HW + y * W_ + x)) * CIN + cc * 64);
        dst[cp] = v;
    }
}

// ---------------- kernel 3: deformable im2col -> smpT[b][p][k] bf16 ----------------
// grid (64 y, 9 kk, 4 b), block 256 = 4 waves.
// lane: c-block = (l&31)*8 channels, p = pair*2 + (l>>5). One 16B gather per corner.
__global__ __launch_bounds__(256) void k_im2col(
    const unsigned short* __restrict__ in_t, const float* __restrict__ off,
    const float* __restrict__ msk, unsigned short* __restrict__ smpT) {
    const int y  = blockIdx.x;
    const int kk = blockIdx.y;
    const int b  = blockIdx.z;
    const int tid = threadIdx.x;

    __shared__ float stw[4][64];
    __shared__ int   stix[4][64];   // pre-scaled by CIN

    if (tid < 64) {
        int x = tid;
        float oy = off[(((size_t)b * 2 * KK_ + 2 * kk + 0) * H_ + y) * W_ + x];
        float ox = off[(((size_t)b * 2 * KK_ + 2 * kk + 1) * H_ + y) * W_ + x];
        float m  = msk[(((size_t)b * KK_ + kk) * H_ + y) * W_ + x];
        float py = (float)(y + kk / 3 - 1) + oy;
        float px = (float)(x + kk % 3 - 1) + ox;
        float y0f = floorf(py), x0f = floorf(px);
        float dy = py - y0f, dx = px - x0f;
        int y0 = (int)y0f, x0 = (int)x0f;
        int y1 = y0 + 1, x1 = x0 + 1;
        bool vy0 = (y0 >= 0) & (y0 < H_), vy1 = (y1 >= 0) & (y1 < H_);
        bool vx0 = (x0 >= 0) & (x0 < W_), vx1 = (x1 >= 0) & (x1 < W_);
        int cy0 = min(max(y0, 0), H_ - 1), cy1 = min(max(y1, 0), H_ - 1);
        int cx0 = min(max(x0, 0), W_ - 1), cx1 = min(max(x1, 0), W_ - 1);
        float wy0 = 1.f - dy, wy1 = dy, wx0 = 1.f - dx, wx1 = dx;
        stw[0][x] = (vy0 && vx0) ? m * wy0 * wx0 : 0.f;  stix[0][x] = (cy0 * W_ + cx0) * CIN;
        stw[1][x] = (vy0 && vx1) ? m * wy0 * wx1 : 0.f;  stix[1][x] = (cy0 * W_ + cx1) * CIN;
        stw[2][x] = (vy1 && vx0) ? m * wy1 * wx0 : 0.f;  stix[2][x] = (cy1 * W_ + cx0) * CIN;
        stw[3][x] = (vy1 && vx1) ? m * wy1 * wx1 : 0.f;  stix[3][x] = (cy1 * W_ + cx1) * CIN;
    }
    __syncthreads();

    const unsigned short* base = in_t + (size_t)b * HW * CIN;
    const int l = tid & 63, w = tid >> 6;
    const int c0 = (l & 31) * 8;
    const int psub = l >> 5;

#pragma unroll
    for (int i = 0; i < 8; ++i) {
        int p = (w + i * 4) * 2 + psub;          // 0..63
        float w0 = stw[0][p], w1 = stw[1][p], w2 = stw[2][p], w3 = stw[3][p];
        bf16x8 v0 = *(const bf16x8*)(base + stix[0][p] + c0);
        bf16x8 v1 = *(const bf16x8*)(base + stix[1][p] + c0);
        bf16x8 v2 = *(const bf16x8*)(base + stix[2][p] + c0);
        bf16x8 v3 = *(const bf16x8*)(base + stix[3][p] + c0);
        bf16x8 r;
#pragma unroll
        for (int j = 0; j < 8; ++j) {
            float a = w0 * (float)v0[j] + w1 * (float)v1[j]
                    + w2 * (float)v2[j] + w3 * (float)v3[j];
            r[j] = (__bf16)a;
        }
        *(bf16x8*)(smpT + ((size_t)(b * HW + y * W_ + p)) * KTOT + kk * CIN + c0) = r;
    }
}

// ---------------- kernel 4: bf16 MFMA GEMM + fused bias/lrelu ----------------
// C[o][p] = sum_k W[o][k] * S[p][k].  Tile 128(O) x 64(P), BK=32, 4 waves.
__global__ __launch_bounds__(256) void k_gemm(
    const unsigned short* __restrict__ wgtT2, const unsigned short* __restrict__ smpT,
    const float* __restrict__ bias1, const float* __restrict__ bias2,
    float* __restrict__ mid) {
    const int p0 = blockIdx.x * 64;
    const int o0 = blockIdx.y * 128;
    const int b  = blockIdx.z;
    const int tid = threadIdx.x;
    const int w  = tid >> 6, l = tid & 63;
    const int lo = l & 15, lg = l >> 4;
    const int wr = w >> 1, wc = w & 1;     // wave -> (o half 64, p half 32)

    __shared__ unsigned short a_lds[128 * 32];   // [o][k] 64B rows
    __shared__ unsigned short b_lds[64 * 32];    // [p][k]

    const unsigned short* Abase = wgtT2 + ((size_t)(b * COUT + o0)) * KTOT;
    const unsigned short* Bbase = smpT  + ((size_t)(b * HW   + p0)) * KTOT;

    f32x4 acc[4][2] = {};

    for (int k0 = 0; k0 < KTOT; k0 += 32) {
        __syncthreads();
        {
            const int j0 = 2 * w;
            const unsigned short* gA0 = Abase + (size_t)(j0 * 16 + (l >> 2)) * KTOT + k0 + (l & 3) * 8;
            gload_lds16(gA0, &a_lds[j0 * 512]);
            const unsigned short* gA1 = Abase + (size_t)((j0 + 1) * 16 + (l >> 2)) * KTOT + k0 + (l & 3) * 8;
            gload_lds16(gA1, &a_lds[(j0 + 1) * 512]);
            const unsigned short* gB = Bbase + (size_t)(w * 16 + (l >> 2)) * KTOT + k0 + (l & 3) * 8;
            gload_lds16(gB, &b_lds[w * 512]);
        }
        __syncthreads();

        bf16x8 af[4], bfr[2];
#pragma unroll
        for (int mi = 0; mi < 4; ++mi)
            af[mi] = *(const bf16x8*)&a_lds[(wr * 64 + mi * 16 + lo) * 32 + lg * 8];
#pragma unroll
        for (int ni = 0; ni < 2; ++ni)
            bfr[ni] = *(const bf16x8*)&b_lds[(wc * 32 + ni * 16 + lo) * 32 + lg * 8];
#pragma unroll
        for (int mi = 0; mi < 4; ++mi)
#pragma unroll
            for (int ni = 0; ni < 2; ++ni)
                acc[mi][ni] = __builtin_amdgcn_mfma_f32_16x16x32_bf16(af[mi], bfr[ni], acc[mi][ni], 0, 0, 0);
    }

    float* mb = mid + ((size_t)b * COUT) * HW;
#pragma unroll
    for (int mi = 0; mi < 4; ++mi) {
        int obase = o0 + wr * 64 + mi * 16 + lg * 4;
#pragma unroll
        for (int ni = 0; ni < 2; ++ni) {
            int p = p0 + wc * 32 + ni * 16 + lo;
#pragma unroll
            for (int r = 0; r < 4; ++r) {
                int oo = obase + r;
                float v = acc[mi][ni][r] + bias1[oo];
                v = (v > 0.f ? v : 0.2f * v) * SQRT2_;
                v += bias2[oo];
                v = (v > 0.f ? v : 0.2f * v) * SQRT2_;
                mb[(size_t)oo * HW + p] = v;
            }
        }
    }
}

// ---------------- kernel 5: x2 upsample + FIR [1,3,3,1] blur ----------------
__global__ void k_blur(const float* __restrict__ mid, float* __restrict__ out) {
    int idx = blockIdx.x * 256 + threadIdx.x;     // 4*256*128*128
    int X = idx & 127;
    int Y = (idx >> 7) & 127;
    int bo = idx >> 14;
    const float* m = mid + (size_t)bo * HW;
    int ry0, ry1; float wy0, wy1;
    if (Y & 1) { ry0 = Y >> 1; wy0 = 3.f; ry1 = (Y >> 1) + 1; wy1 = 1.f; }
    else       { ry0 = (Y >> 1) - 1; wy0 = 1.f; ry1 = Y >> 1; wy1 = 3.f; }
    int rx0, rx1; float wx0, wx1;
    if (X & 1) { rx0 = X >> 1; wx0 = 3.f; rx1 = (X >> 1) + 1; wx1 = 1.f; }
    else       { rx0 = (X >> 1) - 1; wx0 = 1.f; rx1 = X >> 1; wx1 = 3.f; }
    bool vy0 = (ry0 >= 0) & (ry0 < H_), vy1 = (ry1 >= 0) & (ry1 < H_);
    bool vx0 = (rx0 >= 0) & (rx0 < W_), vx1 = (rx1 >= 0) & (rx1 < W_);
    float acc = 0.f;
    if (vy0) {
        const float* r = m + ry0 * W_;
        if (vx0) acc += wy0 * wx0 * r[rx0];
        if (vx1) acc += wy0 * wx1 * r[rx1];
    }
    if (vy1) {
        const float* r = m + ry1 * W_;
        if (vx0) acc += wy1 * wx0 * r[rx0];
        if (vx1) acc += wy1 * wx1 * r[rx1];
    }
    out[idx] = acc * (1.f / 16.f);
}

// ---------------- launch ----------------
extern "C" void kernel_launch(void* const* d_in, const int* in_sizes, int n_in,
                              void* d_out, int out_size, void* d_ws, size_t ws_size,
                              hipStream_t stream) {
    const float* input  = (const float*)d_in[0];
    const float* style  = (const float*)d_in[1];
    const float* offset = (const float*)d_in[2];
    const float* mask   = (const float*)d_in[3];
    const float* weight = (const float*)d_in[4];
    const float* mod_w  = (const float*)d_in[5];
    const float* mod_b  = (const float*)d_in[6];
    const float* bias1  = (const float*)d_in[7];
    const float* bias2  = (const float*)d_in[8];
    float* out = (float*)d_out;

    // ws layout (bytes): s_buf 4K | wgtT2 bf16 4.72M | smpT bf16 75.5M | X 16.8M
    // X region: in_t bf16 (8.4M, dead after k_im2col) aliased with mid f32 (16.8M).
    char* ws = (char*)d_ws;
    float*          s_buf = (float*)ws;
    unsigned short* wgtT2 = (unsigned short*)(ws + 4096);
    unsigned short* smpT  = (unsigned short*)(ws + 4096 + (size_t)B_ * COUT * KTOT * 2);
    char*           X     = ws + 4096 + (size_t)B_ * COUT * KTOT * 2 + (size_t)B_ * HW * KTOT * 2;
    unsigned short* in_t  = (unsigned short*)X;
    float*          mid   = (float*)X;

    k_style <<<dim3(B_), dim3(256), 0, stream>>>(style, mod_w, mod_b, s_buf);
    k_wgt   <<<dim3(COUT, B_), dim3(256), 0, stream>>>(weight, s_buf, wgtT2);
    k_tr    <<<dim3(H_, CIN / 64, B_), dim3(256), 0, stream>>>(input, in_t);
    k_im2col<<<dim3(H_, KK_, B_), dim3(256), 0, stream>>>(in_t, offset, mask, smpT);
    k_gemm  <<<dim3(HW / 64, COUT / 128, B_), dim3(256), 0, stream>>>(wgtT2, smpT, bias1, bias2, mid);
    k_blur  <<<dim3((B_ * COUT * 128 * 128) / 256), dim3(256), 0, stream>>>(mid, out);
}

// Round 4
// 127.860 us; speedup vs baseline: 6.1479x; 1.0995x over previous
//
#include <hip/hip_runtime.h>
#include <math.h>

typedef __bf16 bf16x8 __attribute__((ext_vector_type(8)));
typedef float  f32x4  __attribute__((ext_vector_type(4)));

#define B_    4
#define CIN   256
#define COUT  256
#define KK_   9
#define SD    512
#define H_    64
#define W_    64
#define HW    4096
#define KTOT  2304   // KK_*CIN ; k = kk*CIN + c
#define SCALE_     0.0208333333333333332f   // 1/sqrt(256*9)
#define MOD_SCALE_ 0.04419417382415922f     // 1/sqrt(512)
#define SQRT2_     1.4142135623730951f

__device__ __forceinline__ unsigned short f2bf(float f) {
    union { float f; unsigned int u; } v; v.f = f;
    unsigned int r = v.u + 0x7FFFu + ((v.u >> 16) & 1u);   // RNE
    return (unsigned short)(r >> 16);
}

__device__ __forceinline__ void gload_lds16(const void* g, void* l) {
    __builtin_amdgcn_global_load_lds(
        (const __attribute__((address_space(1))) unsigned int*)g,
        (__attribute__((address_space(3))) unsigned int*)l, 16, 0, 0);
}

// ---------------- kernel 1: style modulation ----------------
__global__ void k_style(const float* __restrict__ style, const float* __restrict__ mod_w,
                        const float* __restrict__ mod_b, float* __restrict__ s_buf) {
    int b = blockIdx.x, c = threadIdx.x;
    const float* st = style + b * SD;
    const float* mw = mod_w + c * SD;
    float acc = 0.f;
    for (int d = 0; d < SD; ++d) acc += st[d] * mw[d];
    s_buf[b * CIN + c] = acc * MOD_SCALE_ + mod_b[c];
}

// ---------------- kernel 2: demodulated weights, bf16, o-major ----------------
// wgtT2[b][o][k], k = kk*CIN + c
__global__ void k_wgt(const float* __restrict__ weight, const float* __restrict__ s_buf,
                      unsigned short* __restrict__ wgtT2) {
    int o = blockIdx.x, b = blockIdx.y;
    int c = threadIdx.x;
    float s = s_buf[b * CIN + c];
    const float* wp = weight + (o * CIN + c) * KK_;
    float w[KK_];
    float p = 0.f;
#pragma unroll
    for (int i = 0; i < KK_; ++i) { w[i] = SCALE_ * wp[i] * s; p += w[i] * w[i]; }
    __shared__ float red[256];
    red[c] = p;
    __syncthreads();
    for (int s2 = 128; s2 > 0; s2 >>= 1) {
        if (c < s2) red[c] += red[c + s2];
        __syncthreads();
    }
    float demod = rsqrtf(red[0] + 1e-8f);
    unsigned short* dst = wgtT2 + ((size_t)(b * COUT + o)) * KTOT + c;
#pragma unroll
    for (int i = 0; i < KK_; ++i) dst[(size_t)i * CIN] = f2bf(w[i] * demod);
}

// ---------------- kernel 2b: input transpose -> in_t[b][y][x][c] bf16 ----------------
__global__ __launch_bounds__(256) void k_tr(const float* __restrict__ in,
                                            unsigned short* __restrict__ in_t) {
    const int y = blockIdx.x, cc = blockIdx.y, b = blockIdx.z;
    const int tid = threadIdx.x;
    __shared__ unsigned short t[64][65];
    for (int e = tid; e < 4096; e += 256) {
        int c = e >> 6, x = e & 63;
        t[c][x] = f2bf(in[((size_t)(b * CIN + cc * 64 + c)) * HW + y * W_ + x]);
    }
    __syncthreads();
    for (int e = tid; e < 2048; e += 256) {
        int x = e >> 5, cp = e & 31;
        int c = cp * 2;
        unsigned int lo = t[c][x], hi = t[c + 1][x];
        unsigned int v = lo | (hi << 16);
        unsigned int* dst = (unsigned int*)(in_t + ((size_t)(b * HW + y * W_ + x)) * CIN + cc * 64);
        dst[cp] = v;
    }
}

// ---------------- kernel 3: deformable im2col -> smpT[b][p][k] bf16 ----------------
__global__ __launch_bounds__(256) void k_im2col(
    const unsigned short* __restrict__ in_t, const float* __restrict__ off,
    const float* __restrict__ msk, unsigned short* __restrict__ smpT) {
    const int y  = blockIdx.x;
    const int kk = blockIdx.y;
    const int b  = blockIdx.z;
    const int tid = threadIdx.x;

    __shared__ float stw[4][64];
    __shared__ int   stix[4][64];   // pre-scaled by CIN

    if (tid < 64) {
        int x = tid;
        float oy = off[(((size_t)b * 2 * KK_ + 2 * kk + 0) * H_ + y) * W_ + x];
        float ox = off[(((size_t)b * 2 * KK_ + 2 * kk + 1) * H_ + y) * W_ + x];
        float m  = msk[(((size_t)b * KK_ + kk) * H_ + y) * W_ + x];
        float py = (float)(y + kk / 3 - 1) + oy;
        float px = (float)(x + kk % 3 - 1) + ox;
        float y0f = floorf(py), x0f = floorf(px);
        float dy = py - y0f, dx = px - x0f;
        int y0 = (int)y0f, x0 = (int)x0f;
        int y1 = y0 + 1, x1 = x0 + 1;
        bool vy0 = (y0 >= 0) & (y0 < H_), vy1 = (y1 >= 0) & (y1 < H_);
        bool vx0 = (x0 >= 0) & (x0 < W_), vx1 = (x1 >= 0) & (x1 < W_);
        int cy0 = min(max(y0, 0), H_ - 1), cy1 = min(max(y1, 0), H_ - 1);
        int cx0 = min(max(x0, 0), W_ - 1), cx1 = min(max(x1, 0), W_ - 1);
        float wy0 = 1.f - dy, wy1 = dy, wx0 = 1.f - dx, wx1 = dx;
        stw[0][x] = (vy0 && vx0) ? m * wy0 * wx0 : 0.f;  stix[0][x] = (cy0 * W_ + cx0) * CIN;
        stw[1][x] = (vy0 && vx1) ? m * wy0 * wx1 : 0.f;  stix[1][x] = (cy0 * W_ + cx1) * CIN;
        stw[2][x] = (vy1 && vx0) ? m * wy1 * wx0 : 0.f;  stix[2][x] = (cy1 * W_ + cx0) * CIN;
        stw[3][x] = (vy1 && vx1) ? m * wy1 * wx1 : 0.f;  stix[3][x] = (cy1 * W_ + cx1) * CIN;
    }
    __syncthreads();

    const unsigned short* base = in_t + (size_t)b * HW * CIN;
    const int l = tid & 63, w = tid >> 6;
    const int c0 = (l & 31) * 8;
    const int psub = l >> 5;

#pragma unroll
    for (int i = 0; i < 8; ++i) {
        int p = (w + i * 4) * 2 + psub;          // 0..63
        float w0 = stw[0][p], w1 = stw[1][p], w2 = stw[2][p], w3 = stw[3][p];
        bf16x8 v0 = *(const bf16x8*)(base + stix[0][p] + c0);
        bf16x8 v1 = *(const bf16x8*)(base + stix[1][p] + c0);
        bf16x8 v2 = *(const bf16x8*)(base + stix[2][p] + c0);
        bf16x8 v3 = *(const bf16x8*)(base + stix[3][p] + c0);
        bf16x8 r;
#pragma unroll
        for (int j = 0; j < 8; ++j) {
            float a = w0 * (float)v0[j] + w1 * (float)v1[j]
                    + w2 * (float)v2[j] + w3 * (float)v3[j];
            r[j] = (__bf16)a;
        }
        *(bf16x8*)(smpT + ((size_t)(b * HW + y * W_ + p)) * KTOT + kk * CIN + c0) = r;
    }
}

// ---------------- kernel 4: bf16 MFMA GEMM, dbuf + swizzled LDS ----------------
// C[o][p] = sum_k W[o][k] * S[p][k]. Tile 128(O) x 64(P), BK=64, 8 waves.
// LDS rows are 128B (64 bf16). Swizzle: 16B-slot s of row r holds global slot s^(r&7);
// staged via inverse-swizzled GLOBAL source (linear LDS dest), read with same XOR.
__global__ __launch_bounds__(512) void k_gemm(
    const unsigned short* __restrict__ wgtT2, const unsigned short* __restrict__ smpT,
    const float* __restrict__ bias1, const float* __restrict__ bias2,
    float* __restrict__ mid) {
    const int p0 = blockIdx.x * 64;
    const int o0 = blockIdx.y * 128;
    const int b  = blockIdx.z;
    const int tid = threadIdx.x;
    const int w  = tid >> 6, l = tid & 63;
    const int lo = l & 15, lg = l >> 4;
    const int wo = w >> 1, wp = w & 1;     // wave -> 32-o x 32-p quadrant

    __shared__ unsigned short a_lds[2][128 * 64];   // [o][k]
    __shared__ unsigned short b_lds[2][64 * 64];    // [p][k]

    const unsigned short* Abase = wgtT2 + ((size_t)(b * COUT + o0)) * KTOT;
    const unsigned short* Bbase = smpT  + ((size_t)(b * HW   + p0)) * KTOT;

    // per-lane staging geometry (row/col within a 1KB chunk = 8 rows)
    const int srow = l >> 3;               // row within chunk
    const int sslot = l & 7;               // 16B slot within 128B row

    f32x4 acc[2][2] = {};

#define STAGE(T, PB)                                                                     \
    do {                                                                                 \
        int kbase = (T) * 64;                                                            \
        int qa0 = 2 * w;                                                                 \
        int ra0 = qa0 * 8 + srow;                                                        \
        gload_lds16(Abase + (size_t)ra0 * KTOT + kbase + ((sslot ^ (ra0 & 7)) * 8),      \
                    &a_lds[PB][qa0 * 512]);                                              \
        int ra1 = ra0 + 8;                                                               \
        gload_lds16(Abase + (size_t)ra1 * KTOT + kbase + ((sslot ^ (ra1 & 7)) * 8),      \
                    &a_lds[PB][(qa0 + 1) * 512]);                                        \
        int rb = w * 8 + srow;                                                           \
        gload_lds16(Bbase + (size_t)rb * KTOT + kbase + ((sslot ^ (rb & 7)) * 8),        \
                    &b_lds[PB][w * 512]);                                                \
    } while (0)

    STAGE(0, 0);
    __syncthreads();

    int cur = 0;
    for (int t = 0; t < 36; ++t) {
        if (t < 35) STAGE(t + 1, cur ^ 1);

        bf16x8 af[2][2], bfr[2][2];
#pragma unroll
        for (int mi = 0; mi < 2; ++mi) {
            int R = wo * 32 + mi * 16 + lo;
#pragma unroll
            for (int kki = 0; kki < 2; ++kki)
                af[mi][kki] = *(const bf16x8*)&a_lds[cur][R * 64 + (((kki * 4 + lg) ^ (R & 7)) * 8)];
        }
#pragma unroll
        for (int ni = 0; ni < 2; ++ni) {
            int P = wp * 32 + ni * 16 + lo;
#pragma unroll
            for (int kki = 0; kki < 2; ++kki)
                bfr[ni][kki] = *(const bf16x8*)&b_lds[cur][P * 64 + (((kki * 4 + lg) ^ (P & 7)) * 8)];
        }
#pragma unroll
        for (int kki = 0; kki < 2; ++kki)
#pragma unroll
            for (int mi = 0; mi < 2; ++mi)
#pragma unroll
                for (int ni = 0; ni < 2; ++ni)
                    acc[mi][ni] = __builtin_amdgcn_mfma_f32_16x16x32_bf16(
                        af[mi][kki], bfr[ni][kki], acc[mi][ni], 0, 0, 0);

        if (t < 35) __syncthreads();   // drains vmcnt(0): next tile staged, cur consumed
        cur ^= 1;
    }
#undef STAGE

    // epilogue: frag D mapping col=lo (p), row=lg*4+r (o)
    float* mb = mid + ((size_t)b * COUT) * HW;
#pragma unroll
    for (int mi = 0; mi < 2; ++mi) {
        int obase = o0 + wo * 32 + mi * 16 + lg * 4;
#pragma unroll
        for (int ni = 0; ni < 2; ++ni) {
            int p = p0 + wp * 32 + ni * 16 + lo;
#pragma unroll
            for (int r = 0; r < 4; ++r) {
                int oo = obase + r;
                float v = acc[mi][ni][r] + bias1[oo];
                v = (v > 0.f ? v : 0.2f * v) * SQRT2_;
                v += bias2[oo];
                v = (v > 0.f ? v : 0.2f * v) * SQRT2_;
                mb[(size_t)oo * HW + p] = v;
            }
        }
    }
}

// ---------------- kernel 5: x2 upsample + FIR [1,3,3,1] blur ----------------
__global__ void k_blur(const float* __restrict__ mid, float* __restrict__ out) {
    int idx = blockIdx.x * 256 + threadIdx.x;     // 4*256*128*128
    int X = idx & 127;
    int Y = (idx >> 7) & 127;
    int bo = idx >> 14;
    const float* m = mid + (size_t)bo * HW;
    int ry0, ry1; float wy0, wy1;
    if (Y & 1) { ry0 = Y >> 1; wy0 = 3.f; ry1 = (Y >> 1) + 1; wy1 = 1.f; }
    else       { ry0 = (Y >> 1) - 1; wy0 = 1.f; ry1 = Y >> 1; wy1 = 3.f; }
    int rx0, rx1; float wx0, wx1;
    if (X & 1) { rx0 = X >> 1; wx0 = 3.f; rx1 = (X >> 1) + 1; wx1 = 1.f; }
    else       { rx0 = (X >> 1) - 1; wx0 = 1.f; rx1 = X >> 1; wx1 = 3.f; }
    bool vy0 = (ry0 >= 0) & (ry0 < H_), vy1 = (ry1 >= 0) & (ry1 < H_);
    bool vx0 = (rx0 >= 0) & (rx0 < W_), vx1 = (rx1 >= 0) & (rx1 < W_);
    float acc = 0.f;
    if (vy0) {
        const float* r = m + ry0 * W_;
        if (vx0) acc += wy0 * wx0 * r[rx0];
        if (vx1) acc += wy0 * wx1 * r[rx1];
    }
    if (vy1) {
        const float* r = m + ry1 * W_;
        if (vx0) acc += wy1 * wx0 * r[rx0];
        if (vx1) acc += wy1 * wx1 * r[rx1];
    }
    out[idx] = acc * (1.f / 16.f);
}

// ---------------- launch ----------------
extern "C" void kernel_launch(void* const* d_in, const int* in_sizes, int n_in,
                              void* d_out, int out_size, void* d_ws, size_t ws_size,
                              hipStream_t stream) {
    const float* input  = (const float*)d_in[0];
    const float* style  = (const float*)d_in[1];
    const float* offset = (const float*)d_in[2];
    const float* mask   = (const float*)d_in[3];
    const float* weight = (const float*)d_in[4];
    const float* mod_w  = (const float*)d_in[5];
    const float* mod_b  = (const float*)d_in[6];
    const float* bias1  = (const float*)d_in[7];
    const float* bias2  = (const float*)d_in[8];
    float* out = (float*)d_out;

    // ws layout (bytes): s_buf 4K | wgtT2 bf16 4.72M | smpT bf16 75.5M | X 16.8M
    // X region: in_t bf16 (8.4M, dead after k_im2col) aliased with mid f32 (16.8M).
    char* ws = (char*)d_ws;
    float*          s_buf = (float*)ws;
    unsigned short* wgtT2 = (unsigned short*)(ws + 4096);
    unsigned short* smpT  = (unsigned short*)(ws + 4096 + (size_t)B_ * COUT * KTOT * 2);
    char*           X     = ws + 4096 + (size_t)B_ * COUT * KTOT * 2 + (size_t)B_ * HW * KTOT * 2;
    unsigned short* in_t  = (unsigned short*)X;
    float*          mid   = (float*)X;

    k_style <<<dim3(B_), dim3(256), 0, stream>>>(style, mod_w, mod_b, s_buf);
    k_wgt   <<<dim3(COUT, B_), dim3(256), 0, stream>>>(weight, s_buf, wgtT2);
    k_tr    <<<dim3(H_, CIN / 64, B_), dim3(256), 0, stream>>>(input, in_t);
    k_im2col<<<dim3(H_, KK_, B_), dim3(256), 0, stream>>>(in_t, offset, mask, smpT);
    k_gemm  <<<dim3(HW / 64, COUT / 128, B_), dim3(512), 0, stream>>>(wgtT2, smpT, bias1, bias2, mid);
    k_blur  <<<dim3((B_ * COUT * 128 * 128) / 256), dim3(256), 0, stream>>>(mid, out);
}

// Round 5
// 99.472 us; speedup vs baseline: 7.9024x; 1.2854x over previous
//
#include <hip/hip_runtime.h>
#include <math.h>

typedef __bf16 bf16x8 __attribute__((ext_vector_type(8)));
typedef float  f32x4  __attribute__((ext_vector_type(4)));

#define B_    4
#define CIN   256
#define COUT  256
#define KK_   9
#define SD    512
#define H_    64
#define W_    64
#define HW    4096
#define KTOT  2304   // KK_*CIN ; k = kk*CIN + c
#define SCALE_     0.0208333333333333332f   // 1/sqrt(256*9)
#define MOD_SCALE_ 0.04419417382415922f     // 1/sqrt(512)
#define SQRT2_     1.4142135623730951f

__device__ __forceinline__ unsigned short f2bf(float f) {
    union { float f; unsigned int u; } v; v.f = f;
    unsigned int r = v.u + 0x7FFFu + ((v.u >> 16) & 1u);   // RNE
    return (unsigned short)(r >> 16);
}

__device__ __forceinline__ void gload_lds16(const void* g, void* l) {
    __builtin_amdgcn_global_load_lds(
        (const __attribute__((address_space(1))) unsigned int*)g,
        (__attribute__((address_space(3))) unsigned int*)l, 16, 0, 0);
}

// ---------------- kernel 1: style modulation ----------------
__global__ void k_style(const float* __restrict__ style, const float* __restrict__ mod_w,
                        const float* __restrict__ mod_b, float* __restrict__ s_buf) {
    int b = blockIdx.x, c = threadIdx.x;
    const float* st = style + b * SD;
    const float* mw = mod_w + c * SD;
    float acc = 0.f;
    for (int d = 0; d < SD; ++d) acc += st[d] * mw[d];
    s_buf[b * CIN + c] = acc * MOD_SCALE_ + mod_b[c];
}

// ---------------- kernel 2: demodulated weights, bf16, o-major ----------------
// wgtT2[b][o][k], k = kk*CIN + c
__global__ void k_wgt(const float* __restrict__ weight, const float* __restrict__ s_buf,
                      unsigned short* __restrict__ wgtT2) {
    int o = blockIdx.x, b = blockIdx.y;
    int c = threadIdx.x;
    float s = s_buf[b * CIN + c];
    const float* wp = weight + (o * CIN + c) * KK_;
    float w[KK_];
    float p = 0.f;
#pragma unroll
    for (int i = 0; i < KK_; ++i) { w[i] = SCALE_ * wp[i] * s; p += w[i] * w[i]; }
    __shared__ float red[256];
    red[c] = p;
    __syncthreads();
    for (int s2 = 128; s2 > 0; s2 >>= 1) {
        if (c < s2) red[c] += red[c + s2];
        __syncthreads();
    }
    float demod = rsqrtf(red[0] + 1e-8f);
    unsigned short* dst = wgtT2 + ((size_t)(b * COUT + o)) * KTOT + c;
#pragma unroll
    for (int i = 0; i < KK_; ++i) dst[(size_t)i * CIN] = f2bf(w[i] * demod);
}

// ---------------- kernel 2b: input transpose -> in_t[b][y][x][c] bf16 ----------------
__global__ __launch_bounds__(256) void k_tr(const float* __restrict__ in,
                                            unsigned short* __restrict__ in_t) {
    const int y = blockIdx.x, cc = blockIdx.y, b = blockIdx.z;
    const int tid = threadIdx.x;
    __shared__ unsigned short t[64][65];
    for (int e = tid; e < 4096; e += 256) {
        int c = e >> 6, x = e & 63;
        t[c][x] = f2bf(in[((size_t)(b * CIN + cc * 64 + c)) * HW + y * W_ + x]);
    }
    __syncthreads();
    for (int e = tid; e < 2048; e += 256) {
        int x = e >> 5, cp = e & 31;
        int c = cp * 2;
        unsigned int lo = t[c][x], hi = t[c + 1][x];
        unsigned int v = lo | (hi << 16);
        unsigned int* dst = (unsigned int*)(in_t + ((size_t)(b * HW + y * W_ + x)) * CIN + cc * 64);
        dst[cp] = v;
    }
}

// ---------------- kernel 3: deformable im2col -> smpT[b][p][k] bf16 ----------------
__global__ __launch_bounds__(256) void k_im2col(
    const unsigned short* __restrict__ in_t, const float* __restrict__ off,
    const float* __restrict__ msk, unsigned short* __restrict__ smpT) {
    const int y  = blockIdx.x;
    const int kk = blockIdx.y;
    const int b  = blockIdx.z;
    const int tid = threadIdx.x;

    __shared__ float stw[4][64];
    __shared__ int   stix[4][64];   // pre-scaled by CIN

    if (tid < 64) {
        int x = tid;
        float oy = off[(((size_t)b * 2 * KK_ + 2 * kk + 0) * H_ + y) * W_ + x];
        float ox = off[(((size_t)b * 2 * KK_ + 2 * kk + 1) * H_ + y) * W_ + x];
        float m  = msk[(((size_t)b * KK_ + kk) * H_ + y) * W_ + x];
        float py = (float)(y + kk / 3 - 1) + oy;
        float px = (float)(x + kk % 3 - 1) + ox;
        float y0f = floorf(py), x0f = floorf(px);
        float dy = py - y0f, dx = px - x0f;
        int y0 = (int)y0f, x0 = (int)x0f;
        int y1 = y0 + 1, x1 = x0 + 1;
        bool vy0 = (y0 >= 0) & (y0 < H_), vy1 = (y1 >= 0) & (y1 < H_);
        bool vx0 = (x0 >= 0) & (x0 < W_), vx1 = (x1 >= 0) & (x1 < W_);
        int cy0 = min(max(y0, 0), H_ - 1), cy1 = min(max(y1, 0), H_ - 1);
        int cx0 = min(max(x0, 0), W_ - 1), cx1 = min(max(x1, 0), W_ - 1);
        float wy0 = 1.f - dy, wy1 = dy, wx0 = 1.f - dx, wx1 = dx;
        stw[0][x] = (vy0 && vx0) ? m * wy0 * wx0 : 0.f;  stix[0][x] = (cy0 * W_ + cx0) * CIN;
        stw[1][x] = (vy0 && vx1) ? m * wy0 * wx1 : 0.f;  stix[1][x] = (cy0 * W_ + cx1) * CIN;
        stw[2][x] = (vy1 && vx0) ? m * wy1 * wx0 : 0.f;  stix[2][x] = (cy1 * W_ + cx0) * CIN;
        stw[3][x] = (vy1 && vx1) ? m * wy1 * wx1 : 0.f;  stix[3][x] = (cy1 * W_ + cx1) * CIN;
    }
    __syncthreads();

    const unsigned short* base = in_t + (size_t)b * HW * CIN;
    const int l = tid & 63, w = tid >> 6;
    const int c0 = (l & 31) * 8;
    const int psub = l >> 5;

#pragma unroll
    for (int i = 0; i < 8; ++i) {
        int p = (w + i * 4) * 2 + psub;          // 0..63
        float w0 = stw[0][p], w1 = stw[1][p], w2 = stw[2][p], w3 = stw[3][p];
        bf16x8 v0 = *(const bf16x8*)(base + stix[0][p] + c0);
        bf16x8 v1 = *(const bf16x8*)(base + stix[1][p] + c0);
        bf16x8 v2 = *(const bf16x8*)(base + stix[2][p] + c0);
        bf16x8 v3 = *(const bf16x8*)(base + stix[3][p] + c0);
        bf16x8 r;
#pragma unroll
        for (int j = 0; j < 8; ++j) {
            float a = w0 * (float)v0[j] + w1 * (float)v1[j]
                    + w2 * (float)v2[j] + w3 * (float)v3[j];
            r[j] = (__bf16)a;
        }
        *(bf16x8*)(smpT + ((size_t)(b * HW + y * W_ + p)) * KTOT + kk * CIN + c0) = r;
    }
}

// ---------------- kernel 4: bf16 MFMA GEMM, dbuf + swizzled LDS ----------------
// C[o][p] = sum_k W[o][k] * S[p][k]. Tile 128(O) x 64(P), BK=64, 8 waves.
__global__ __launch_bounds__(512) void k_gemm(
    const unsigned short* __restrict__ wgtT2, const unsigned short* __restrict__ smpT,
    const float* __restrict__ bias1, const float* __restrict__ bias2,
    float* __restrict__ mid) {
    const int p0 = blockIdx.x * 64;
    const int o0 = blockIdx.y * 128;
    const int b  = blockIdx.z;
    const int tid = threadIdx.x;
    const int w  = tid >> 6, l = tid & 63;
    const int lo = l & 15, lg = l >> 4;
    const int wo = w >> 1, wp = w & 1;     // wave -> 32-o x 32-p quadrant

    __shared__ unsigned short a_lds[2][128 * 64];   // [o][k]
    __shared__ unsigned short b_lds[2][64 * 64];    // [p][k]

    const unsigned short* Abase = wgtT2 + ((size_t)(b * COUT + o0)) * KTOT;
    const unsigned short* Bbase = smpT  + ((size_t)(b * HW   + p0)) * KTOT;

    const int srow = l >> 3;               // row within chunk
    const int sslot = l & 7;               // 16B slot within 128B row

    f32x4 acc[2][2] = {};

#define STAGE(T, PB)                                                                     \
    do {                                                                                 \
        int kbase = (T) * 64;                                                            \
        int qa0 = 2 * w;                                                                 \
        int ra0 = qa0 * 8 + srow;                                                        \
        gload_lds16(Abase + (size_t)ra0 * KTOT + kbase + ((sslot ^ (ra0 & 7)) * 8),      \
                    &a_lds[PB][qa0 * 512]);                                              \
        int ra1 = ra0 + 8;                                                               \
        gload_lds16(Abase + (size_t)ra1 * KTOT + kbase + ((sslot ^ (ra1 & 7)) * 8),      \
                    &a_lds[PB][(qa0 + 1) * 512]);                                        \
        int rb = w * 8 + srow;                                                           \
        gload_lds16(Bbase + (size_t)rb * KTOT + kbase + ((sslot ^ (rb & 7)) * 8),        \
                    &b_lds[PB][w * 512]);                                                \
    } while (0)

    STAGE(0, 0);
    __syncthreads();

    int cur = 0;
    for (int t = 0; t < 36; ++t) {
        if (t < 35) STAGE(t + 1, cur ^ 1);

        bf16x8 af[2][2], bfr[2][2];
#pragma unroll
        for (int mi = 0; mi < 2; ++mi) {
            int R = wo * 32 + mi * 16 + lo;
#pragma unroll
            for (int kki = 0; kki < 2; ++kki)
                af[mi][kki] = *(const bf16x8*)&a_lds[cur][R * 64 + (((kki * 4 + lg) ^ (R & 7)) * 8)];
        }
#pragma unroll
        for (int ni = 0; ni < 2; ++ni) {
            int P = wp * 32 + ni * 16 + lo;
#pragma unroll
            for (int kki = 0; kki < 2; ++kki)
                bfr[ni][kki] = *(const bf16x8*)&b_lds[cur][P * 64 + (((kki * 4 + lg) ^ (P & 7)) * 8)];
        }
#pragma unroll
        for (int kki = 0; kki < 2; ++kki)
#pragma unroll
            for (int mi = 0; mi < 2; ++mi)
#pragma unroll
                for (int ni = 0; ni < 2; ++ni)
                    acc[mi][ni] = __builtin_amdgcn_mfma_f32_16x16x32_bf16(
                        af[mi][kki], bfr[ni][kki], acc[mi][ni], 0, 0, 0);

        if (t < 35) __syncthreads();
        cur ^= 1;
    }
#undef STAGE

    float* mb = mid + ((size_t)b * COUT) * HW;
#pragma unroll
    for (int mi = 0; mi < 2; ++mi) {
        int obase = o0 + wo * 32 + mi * 16 + lg * 4;
#pragma unroll
        for (int ni = 0; ni < 2; ++ni) {
            int p = p0 + wp * 32 + ni * 16 + lo;
#pragma unroll
            for (int r = 0; r < 4; ++r) {
                int oo = obase + r;
                float v = acc[mi][ni][r] + bias1[oo];
                v = (v > 0.f ? v : 0.2f * v) * SQRT2_;
                v += bias2[oo];
                v = (v > 0.f ? v : 0.2f * v) * SQRT2_;
                mb[(size_t)oo * HW + p] = v;
            }
        }
    }
}

// ---------------- kernel 5: separable x2-upsample FIR blur ----------------
// One block per (b,o) channel. Stage mid channel in LDS, vertical pass to vt,
// horizontal pass emits float4 (4 output px from 4 LDS reads).
__global__ __launch_bounds__(256) void k_blur(const float* __restrict__ mid,
                                              float* __restrict__ out) {
    const int bo = blockIdx.x;
    const int tid = threadIdx.x;
    __shared__ float m[64][64];        // 16 KB
    __shared__ float vt[128][65];      // padded: wave halves hit disjoint banks

    const float4* src = (const float4*)(mid + (size_t)bo * HW);
#pragma unroll
    for (int i = 0; i < 4; ++i)
        ((float4*)m)[tid + 256 * i] = src[tid + 256 * i];
    __syncthreads();

    // vertical: vt[Y][x] = wy0*m[ry0][x] + wy1*m[ry1][x]
#pragma unroll
    for (int i = 0; i < 32; ++i) {
        int e = tid + 256 * i;
        int Y = e >> 6, x = e & 63;
        int h = Y >> 1;
        float acc;
        if (Y & 1) acc = 3.f * m[h][x] + ((h + 1 < 64) ? m[h + 1][x] : 0.f);
        else       acc = ((h >= 1) ? m[h - 1][x] : 0.f) + 3.f * m[h][x];
        vt[Y][x] = acc;
    }
    __syncthreads();

    // horizontal: 4 outputs per thread-iter from cols 2t-1..2t+2
    float4* dst = (float4*)(out + (size_t)bo * 128 * 128);
#pragma unroll
    for (int i = 0; i < 16; ++i) {
        int e = tid + 256 * i;
        int Y = e >> 5, t = e & 31;
        const float* v = vt[Y];
        int c = 2 * t;
        float vm1 = (c >= 1) ? v[c - 1] : 0.f;
        float v0 = v[c];
        float v1 = v[c + 1];
        float vp2 = (c + 2 < 64) ? v[c + 2] : 0.f;
        float4 r;
        r.x = (vm1 + 3.f * v0) * (1.f / 16.f);
        r.y = (3.f * v0 + v1)  * (1.f / 16.f);
        r.z = (v0 + 3.f * v1)  * (1.f / 16.f);
        r.w = (3.f * v1 + vp2) * (1.f / 16.f);
        dst[e] = r;
    }
}

// ---------------- launch ----------------
extern "C" void kernel_launch(void* const* d_in, const int* in_sizes, int n_in,
                              void* d_out, int out_size, void* d_ws, size_t ws_size,
                              hipStream_t stream) {
    const float* input  = (const float*)d_in[0];
    const float* style  = (const float*)d_in[1];
    const float* offset = (const float*)d_in[2];
    const float* mask   = (const float*)d_in[3];
    const float* weight = (const float*)d_in[4];
    const float* mod_w  = (const float*)d_in[5];
    const float* mod_b  = (const float*)d_in[6];
    const float* bias1  = (const float*)d_in[7];
    const float* bias2  = (const float*)d_in[8];
    float* out = (float*)d_out;

    // ws layout (bytes): s_buf 4K | wgtT2 bf16 4.72M | smpT bf16 75.5M | X 16.8M
    // X region: in_t bf16 (8.4M, dead after k_im2col) aliased with mid f32 (16.8M).
    char* ws = (char*)d_ws;
    float*          s_buf = (float*)ws;
    unsigned short* wgtT2 = (unsigned short*)(ws + 4096);
    unsigned short* smpT  = (unsigned short*)(ws + 4096 + (size_t)B_ * COUT * KTOT * 2);
    char*           X     = ws + 4096 + (size_t)B_ * COUT * KTOT * 2 + (size_t)B_ * HW * KTOT * 2;
    unsigned short* in_t  = (unsigned short*)X;
    float*          mid   = (float*)X;

    k_style <<<dim3(B_), dim3(256), 0, stream>>>(style, mod_w, mod_b, s_buf);
    k_wgt   <<<dim3(COUT, B_), dim3(256), 0, stream>>>(weight, s_buf, wgtT2);
    k_tr    <<<dim3(H_, CIN / 64, B_), dim3(256), 0, stream>>>(input, in_t);
    k_im2col<<<dim3(H_, KK_, B_), dim3(256), 0, stream>>>(in_t, offset, mask, smpT);
    k_gemm  <<<dim3(HW / 64, COUT / 128, B_), dim3(512), 0, stream>>>(wgtT2, smpT, bias1, bias2, mid);
    k_blur  <<<dim3(B_ * COUT), dim3(256), 0, stream>>>(mid, out);
}